// Round 1
// baseline (695.675 us; speedup 1.0000x reference)
//
#include <hip/hip_runtime.h>
#include <cstdint>
#include <cstddef>

// ---------------- CSR construction ----------------

__global__ void hist_k(const int* __restrict__ recv, int* __restrict__ hist, int E){
  int i = blockIdx.x*blockDim.x + threadIdx.x;
  if (i < E) atomicAdd(&hist[recv[i]], 1);
}

__global__ void s1_k(const int* __restrict__ hist, int* __restrict__ partial, int Nn){
  __shared__ int sh[256];
  int t = threadIdx.x;
  int i = blockIdx.x*256 + t;
  sh[t] = (i < Nn) ? hist[i] : 0;
  __syncthreads();
  for (int off = 128; off > 0; off >>= 1){
    if (t < off) sh[t] += sh[t + off];
    __syncthreads();
  }
  if (t == 0) partial[blockIdx.x] = sh[0];
}

__global__ void s2_k(int* __restrict__ partial, int nb){
  if (blockIdx.x == 0 && threadIdx.x == 0){
    int run = 0;
    for (int b = 0; b < nb; b++){ int v = partial[b]; partial[b] = run; run += v; }
  }
}

__global__ void s3_k(const int* __restrict__ hist, const int* __restrict__ partial,
                     int* __restrict__ offsets, int* __restrict__ cursor, int Nn){
  __shared__ int sh[256];
  int t = threadIdx.x;
  int i = blockIdx.x*256 + t;
  int v = (i < Nn) ? hist[i] : 0;
  sh[t] = v;
  __syncthreads();
  for (int off = 1; off < 256; off <<= 1){
    int x = (t >= off) ? sh[t - off] : 0;
    __syncthreads();
    sh[t] += x;
    __syncthreads();
  }
  if (i < Nn){
    int excl = sh[t] - v + partial[blockIdx.x];
    offsets[i] = excl;
    cursor[i]  = excl;
  }
}

__global__ void fill_k(const int* __restrict__ recv, int* __restrict__ cursor,
                       int* __restrict__ csr, int E){
  int i = blockIdx.x*blockDim.x + threadIdx.x;
  if (i < E){
    int r = recv[i];
    int pos = atomicAdd(&cursor[r], 1);
    csr[pos] = i;
  }
}

// ---------------- atomic-free segment sum of RAW features ----------------
// SE[node][0:64]  = sum over incoming edges of nodes[senders[e]]
// SE[node][64:128]= sum over incoming edges of edges[e]
__global__ __launch_bounds__(256) void gather_sum_k(
    const float* __restrict__ nodes, const float* __restrict__ edges,
    const int* __restrict__ senders, const int* __restrict__ offsets,
    const int* __restrict__ hist, const int* __restrict__ csr,
    float* __restrict__ SE, int Nn)
{
  int wid  = threadIdx.x >> 6;
  int lane = threadIdx.x & 63;
  int node = blockIdx.x*4 + wid;
  if (node >= Nn) return;
  int start = offsets[node];
  int cnt   = hist[node];
  float sa = 0.f, ea = 0.f;
  int i = 0;
  for (; i + 2 <= cnt; i += 2){
    int e0 = csr[start + i], e1 = csr[start + i + 1];
    int s0 = senders[e0],    s1 = senders[e1];
    float n0 = nodes[(size_t)s0*64 + lane];
    float n1 = nodes[(size_t)s1*64 + lane];
    float g0 = edges[(size_t)e0*64 + lane];
    float g1 = edges[(size_t)e1*64 + lane];
    sa += n0 + n1;
    ea += g0 + g1;
  }
  if (i < cnt){
    int e0 = csr[start + i];
    int s0 = senders[e0];
    sa += nodes[(size_t)s0*64 + lane];
    ea += edges[(size_t)e0*64 + lane];
  }
  SE[(size_t)node*128 + lane]      = sa;
  SE[(size_t)node*128 + 64 + lane] = ea;
}

// ---------------- tiled transpose [R][C] -> [C][R] ----------------
__global__ void transpose_k(const float* __restrict__ in, float* __restrict__ out, int R, int C){
  __shared__ float tile[32][33];
  int c0 = blockIdx.x*32, r0 = blockIdx.y*32;
  int tx = threadIdx.x, ty = threadIdx.y;
  #pragma unroll
  for (int i = 0; i < 32; i += 8){
    int r = r0 + ty + i, c = c0 + tx;
    if (r < R && c < C) tile[ty + i][tx] = in[(size_t)r*C + c];
  }
  __syncthreads();
  #pragma unroll
  for (int i = 0; i < 32; i += 8){
    int c = c0 + ty + i, r = r0 + tx;
    if (r < R && c < C) out[(size_t)c*R + r] = tile[tx][ty + i];
  }
}

// ---------------- weight folding ----------------
// W1eff[192][128]: rows 0..63  = w0[0:64]   (node features)
//                  rows 64..191= Wmsg @ w0[64:128]   (raw SE features)
// W3eff[192][64]:  rows 0..127 = w2 ; rows 128..191 = W_node  (residual fold)
__global__ void wprep_k(const float* __restrict__ Wmsg, const float* __restrict__ w0,
                        const float* __restrict__ w2, const float* __restrict__ Wnode,
                        float* __restrict__ W1eff, float* __restrict__ W3eff){
  int idx = blockIdx.x*blockDim.x + threadIdx.x;
  if (idx < 192*128){
    int r = idx >> 7, j = idx & 127;
    float v;
    if (r < 64) v = w0[r*128 + j];
    else {
      int kk = r - 64;
      float a = 0.f;
      for (int m = 0; m < 64; m++) a = fmaf(Wmsg[kk*64 + m], w0[(64 + m)*128 + j], a);
      v = a;
    }
    W1eff[idx] = v;
  }
  if (idx < 192*64){
    int r = idx >> 6, j = idx & 63;
    W3eff[idx] = (r < 128) ? w2[r*64 + j] : Wnode[(r - 128)*64 + j];
  }
}

// ---------------- MLP layers, lane-per-node on transposed activations ----------------

__global__ __launch_bounds__(256) void layer1_k(
    const float* __restrict__ nodesT, const float* __restrict__ SET,
    const float* __restrict__ W, const float* __restrict__ bias,
    float* __restrict__ outT, int N)
{
  int n  = blockIdx.x*256 + threadIdx.x;
  int jb = blockIdx.y*32;
  if (n >= N) return;
  float acc[32];
  #pragma unroll
  for (int j = 0; j < 32; j++) acc[j] = bias[jb + j];
  for (int k = 0; k < 64; k++){
    float x = nodesT[(size_t)k*N + n];
    #pragma unroll
    for (int j = 0; j < 32; j++) acc[j] = fmaf(x, W[k*128 + jb + j], acc[j]);
  }
  for (int k = 0; k < 128; k++){
    float x = SET[(size_t)k*N + n];
    #pragma unroll
    for (int j = 0; j < 32; j++) acc[j] = fmaf(x, W[(64 + k)*128 + jb + j], acc[j]);
  }
  #pragma unroll
  for (int j = 0; j < 32; j++) outT[(size_t)(jb + j)*N + n] = fmaxf(acc[j], 0.f);
}

__global__ __launch_bounds__(256) void layer2_k(
    const float* __restrict__ inT, const float* __restrict__ W, const float* __restrict__ bias,
    float* __restrict__ outT, int N)
{
  int n  = blockIdx.x*256 + threadIdx.x;
  int jb = blockIdx.y*32;
  if (n >= N) return;
  float acc[32];
  #pragma unroll
  for (int j = 0; j < 32; j++) acc[j] = bias[jb + j];
  for (int k = 0; k < 128; k++){
    float x = inT[(size_t)k*N + n];
    #pragma unroll
    for (int j = 0; j < 32; j++) acc[j] = fmaf(x, W[k*128 + jb + j], acc[j]);
  }
  #pragma unroll
  for (int j = 0; j < 32; j++) outT[(size_t)(jb + j)*N + n] = fmaxf(acc[j], 0.f);
}

__global__ __launch_bounds__(256) void layer3_k(
    const float* __restrict__ X2T, const float* __restrict__ nodesT,
    const float* __restrict__ W, const float* __restrict__ bias,
    const float* __restrict__ ln_scale, const float* __restrict__ ln_bias,
    float* __restrict__ out, int N)
{
  int n = blockIdx.x*256 + threadIdx.x;
  if (n >= N) return;
  float acc[64];
  #pragma unroll
  for (int j = 0; j < 64; j++) acc[j] = bias[j];
  for (int k = 0; k < 128; k++){
    float x = X2T[(size_t)k*N + n];
    #pragma unroll
    for (int j = 0; j < 64; j++) acc[j] = fmaf(x, W[k*64 + j], acc[j]);
  }
  for (int k = 0; k < 64; k++){
    float x = nodesT[(size_t)k*N + n];
    #pragma unroll
    for (int j = 0; j < 64; j++) acc[j] = fmaf(x, W[(128 + k)*64 + j], acc[j]);
  }
  float mu = 0.f;
  #pragma unroll
  for (int j = 0; j < 64; j++) mu += acc[j];
  mu *= (1.f/64.f);
  float var = 0.f;
  #pragma unroll
  for (int j = 0; j < 64; j++){ float d = acc[j] - mu; var = fmaf(d, d, var); }
  var *= (1.f/64.f);
  float inv = rsqrtf(var + 1e-6f);
  float4* o = (float4*)(out + (size_t)n*64);
  #pragma unroll
  for (int q = 0; q < 16; q++){
    float y0 = (acc[4*q+0] - mu)*inv*ln_scale[4*q+0] + ln_bias[4*q+0];
    float y1 = (acc[4*q+1] - mu)*inv*ln_scale[4*q+1] + ln_bias[4*q+1];
    float y2 = (acc[4*q+2] - mu)*inv*ln_scale[4*q+2] + ln_bias[4*q+2];
    float y3 = (acc[4*q+3] - mu)*inv*ln_scale[4*q+3] + ln_bias[4*q+3];
    o[q] = make_float4(y0, y1, y2, y3);
  }
}

// ---------------- launch ----------------

extern "C" void kernel_launch(void* const* d_in, const int* in_sizes, int n_in,
                              void* d_out, int out_size, void* d_ws, size_t ws_size,
                              hipStream_t stream)
{
  const float* nodes   = (const float*)d_in[0];
  const float* edges   = (const float*)d_in[1];
  const int*   senders = (const int*)d_in[2];
  const int*   recv    = (const int*)d_in[3];
  const float* Wmsg    = (const float*)d_in[4];
  const float* Wnode   = (const float*)d_in[5];
  const float* w0      = (const float*)d_in[6];
  const float* b0      = (const float*)d_in[7];
  const float* w1      = (const float*)d_in[8];
  const float* b1      = (const float*)d_in[9];
  const float* w2      = (const float*)d_in[10];
  const float* b2      = (const float*)d_in[11];
  const float* lns     = (const float*)d_in[12];
  const float* lnb     = (const float*)d_in[13];
  float* out = (float*)d_out;

  const int N = in_sizes[0] / 64;
  const int E = in_sizes[2];

  auto align256 = [](size_t x){ return (x + 255) & ~(size_t)255; };
  char* p = (char*)d_ws;
  int* hist    = (int*)p; p += align256((size_t)N*4);
  int* offsets = (int*)p; p += align256((size_t)N*4);
  int* cursor  = (int*)p; p += align256((size_t)N*4);
  int* partial = (int*)p; p += align256(1024);
  int* csr     = (int*)p; p += align256((size_t)E*4);
  float* W1eff = (float*)p; p += align256((size_t)192*128*4);
  float* W3eff = (float*)p; p += align256((size_t)192*64*4);
  float* nodesT= (float*)p; p += align256((size_t)64*N*4);
  float* bufA  = (float*)p; p += align256((size_t)128*N*4);  // SE row-major, later X1_T
  float* bufB  = (float*)p; p += align256((size_t)128*N*4);  // SE_T, later X2_T

  hipMemsetAsync(hist, 0, (size_t)N*4, stream);

  const int gridE = (E + 255)/256;
  const int nb    = (N + 255)/256;

  hist_k<<<gridE, 256, 0, stream>>>(recv, hist, E);
  s1_k<<<nb, 256, 0, stream>>>(hist, partial, N);
  s2_k<<<1, 64, 0, stream>>>(partial, nb);
  s3_k<<<nb, 256, 0, stream>>>(hist, partial, offsets, cursor, N);
  fill_k<<<gridE, 256, 0, stream>>>(recv, cursor, csr, E);

  gather_sum_k<<<(N + 3)/4, 256, 0, stream>>>(nodes, edges, senders, offsets, hist, csr, bufA, N);

  dim3 tb(32, 8);
  transpose_k<<<dim3(2, (N + 31)/32), tb, 0, stream>>>(nodes, nodesT, N, 64);
  transpose_k<<<dim3(4, (N + 31)/32), tb, 0, stream>>>(bufA, bufB, N, 128);

  wprep_k<<<(192*128 + 255)/256, 256, 0, stream>>>(Wmsg, w0, w2, Wnode, W1eff, W3eff);

  layer1_k<<<dim3(nb, 4), 256, 0, stream>>>(nodesT, bufB, W1eff, b0, bufA, N);
  layer2_k<<<dim3(nb, 4), 256, 0, stream>>>(bufA, w1, b1, bufB, N);
  layer3_k<<<nb, 256, 0, stream>>>(bufB, nodesT, W3eff, b2, lns, lnb, out, N);
}

// Round 2
// 644.420 us; speedup vs baseline: 1.0795x; 1.0795x over previous
//
#include <hip/hip_runtime.h>
#include <cstdint>
#include <cstddef>

// ---------------- CSR construction ----------------

__global__ void hist_k(const int* __restrict__ recv, int* __restrict__ hist, int E){
  int i = blockIdx.x*blockDim.x + threadIdx.x;
  if (i < E) atomicAdd(&hist[recv[i]], 1);
}

__global__ void s1_k(const int* __restrict__ hist, int* __restrict__ partial, int Nn){
  __shared__ int sh[256];
  int t = threadIdx.x;
  int i = blockIdx.x*256 + t;
  sh[t] = (i < Nn) ? hist[i] : 0;
  __syncthreads();
  for (int off = 128; off > 0; off >>= 1){
    if (t < off) sh[t] += sh[t + off];
    __syncthreads();
  }
  if (t == 0) partial[blockIdx.x] = sh[0];
}

// single-wave exclusive scan over nb block sums
__global__ void s2_k(int* __restrict__ partial, int nb){
  int lane = threadIdx.x;  // 64 threads
  int run = 0;
  for (int base = 0; base < nb; base += 64){
    int v = (base + lane < nb) ? partial[base + lane] : 0;
    int x = v;
    #pragma unroll
    for (int off = 1; off < 64; off <<= 1){
      int y = __shfl_up(x, off);
      if (lane >= off) x += y;
    }
    if (base + lane < nb) partial[base + lane] = x - v + run;
    run += __shfl(x, 63);
  }
}

__global__ void s3_k(const int* __restrict__ hist, const int* __restrict__ partial,
                     int* __restrict__ offsets, int* __restrict__ cursor, int Nn){
  __shared__ int sh[256];
  int t = threadIdx.x;
  int i = blockIdx.x*256 + t;
  int v = (i < Nn) ? hist[i] : 0;
  sh[t] = v;
  __syncthreads();
  for (int off = 1; off < 256; off <<= 1){
    int x = (t >= off) ? sh[t - off] : 0;
    __syncthreads();
    sh[t] += x;
    __syncthreads();
  }
  if (i < Nn){
    int excl = sh[t] - v + partial[blockIdx.x];
    offsets[i] = excl;
    cursor[i]  = excl;
  }
}

// packed CSR: (edge index, sender) per slot
__global__ void fill_k(const int* __restrict__ recv, const int* __restrict__ senders,
                       int* __restrict__ cursor, int2* __restrict__ csr_pack, int E){
  int i = blockIdx.x*blockDim.x + threadIdx.x;
  if (i < E){
    int r = recv[i];
    int s = senders[i];
    int pos = atomicAdd(&cursor[r], 1);
    csr_pack[pos] = make_int2(i, s);
  }
}

// ---------------- atomic-free segment sum of RAW features ----------------
// SE[node][0:64]  = sum over incoming edges of nodes[senders[e]]
// SE[node][64:128]= sum over incoming edges of edges[e]
// One wave per node. Indices fetched coalesced (one packed entry per lane),
// then shfl-broadcast; row loads unrolled 4x -> 8 independent 256B loads in flight.
__global__ __launch_bounds__(256) void gather_sum_k(
    const float* __restrict__ nodes, const float* __restrict__ edges,
    const int2* __restrict__ csr_pack, const int* __restrict__ offsets,
    const int* __restrict__ hist, float* __restrict__ SE, int Nn)
{
  int wid  = threadIdx.x >> 6;
  int lane = threadIdx.x & 63;
  int node = blockIdx.x*4 + wid;
  if (node >= Nn) return;
  int start = offsets[node];
  int cnt   = hist[node];
  float sa = 0.f, ea = 0.f;
  int done = 0;
  while (done < cnt){
    int m = cnt - done; if (m > 64) m = 64;
    int2 pk = make_int2(0, 0);
    if (lane < m) pk = csr_pack[start + done + lane];
    int u = 0;
    for (; u + 4 <= m; u += 4){
      int e0 = __shfl(pk.x, u+0), s0 = __shfl(pk.y, u+0);
      int e1 = __shfl(pk.x, u+1), s1 = __shfl(pk.y, u+1);
      int e2 = __shfl(pk.x, u+2), s2 = __shfl(pk.y, u+2);
      int e3 = __shfl(pk.x, u+3), s3 = __shfl(pk.y, u+3);
      float n0 = nodes[(size_t)s0*64 + lane];
      float n1 = nodes[(size_t)s1*64 + lane];
      float n2 = nodes[(size_t)s2*64 + lane];
      float n3 = nodes[(size_t)s3*64 + lane];
      float g0 = edges[(size_t)e0*64 + lane];
      float g1 = edges[(size_t)e1*64 + lane];
      float g2 = edges[(size_t)e2*64 + lane];
      float g3 = edges[(size_t)e3*64 + lane];
      sa += (n0 + n1) + (n2 + n3);
      ea += (g0 + g1) + (g2 + g3);
    }
    for (; u < m; u++){
      int e0 = __shfl(pk.x, u), s0 = __shfl(pk.y, u);
      sa += nodes[(size_t)s0*64 + lane];
      ea += edges[(size_t)e0*64 + lane];
    }
    done += m;
  }
  SE[(size_t)node*128 + lane]      = sa;
  SE[(size_t)node*128 + 64 + lane] = ea;
}

// ---------------- tiled transpose [R][C] -> [C][R] ----------------
__global__ void transpose_k(const float* __restrict__ in, float* __restrict__ out, int R, int C){
  __shared__ float tile[32][33];
  int c0 = blockIdx.x*32, r0 = blockIdx.y*32;
  int tx = threadIdx.x, ty = threadIdx.y;
  #pragma unroll
  for (int i = 0; i < 32; i += 8){
    int r = r0 + ty + i, c = c0 + tx;
    if (r < R && c < C) tile[ty + i][tx] = in[(size_t)r*C + c];
  }
  __syncthreads();
  #pragma unroll
  for (int i = 0; i < 32; i += 8){
    int c = c0 + ty + i, r = r0 + tx;
    if (r < R && c < C) out[(size_t)c*R + r] = tile[tx][ty + i];
  }
}

// ---------------- weight folding ----------------
// W1eff[192][128]: rows 0..63  = w0[0:64]   (node features)
//                  rows 64..191= Wmsg @ w0[64:128]   (raw SE features)
// W3eff[192][64]:  rows 0..127 = w2 ; rows 128..191 = W_node  (residual fold)
__global__ void wprep_k(const float* __restrict__ Wmsg, const float* __restrict__ w0,
                        const float* __restrict__ w2, const float* __restrict__ Wnode,
                        float* __restrict__ W1eff, float* __restrict__ W3eff){
  int idx = blockIdx.x*blockDim.x + threadIdx.x;
  if (idx < 192*128){
    int r = idx >> 7, j = idx & 127;
    float v;
    if (r < 64) v = w0[r*128 + j];
    else {
      int kk = r - 64;
      float a = 0.f;
      for (int m = 0; m < 64; m++) a = fmaf(Wmsg[kk*64 + m], w0[(64 + m)*128 + j], a);
      v = a;
    }
    W1eff[idx] = v;
  }
  if (idx < 192*64){
    int r = idx >> 6, j = idx & 63;
    W3eff[idx] = (r < 128) ? w2[r*64 + j] : Wnode[(r - 128)*64 + j];
  }
}

// ---------------- MLP layers, lane-per-node on transposed activations ----------------

__global__ __launch_bounds__(256) void layer1_k(
    const float* __restrict__ nodesT, const float* __restrict__ SET,
    const float* __restrict__ W, const float* __restrict__ bias,
    float* __restrict__ outT, int N)
{
  int n  = blockIdx.x*256 + threadIdx.x;
  int jb = blockIdx.y*64;
  if (n >= N) return;
  float acc[64];
  #pragma unroll
  for (int j = 0; j < 64; j++) acc[j] = bias[jb + j];
  for (int k = 0; k < 64; k++){
    float x = nodesT[(size_t)k*N + n];
    #pragma unroll
    for (int j = 0; j < 64; j++) acc[j] = fmaf(x, W[k*128 + jb + j], acc[j]);
  }
  for (int k = 0; k < 128; k++){
    float x = SET[(size_t)k*N + n];
    #pragma unroll
    for (int j = 0; j < 64; j++) acc[j] = fmaf(x, W[(64 + k)*128 + jb + j], acc[j]);
  }
  #pragma unroll
  for (int j = 0; j < 64; j++) outT[(size_t)(jb + j)*N + n] = fmaxf(acc[j], 0.f);
}

__global__ __launch_bounds__(256) void layer2_k(
    const float* __restrict__ inT, const float* __restrict__ W, const float* __restrict__ bias,
    float* __restrict__ outT, int N)
{
  int n  = blockIdx.x*256 + threadIdx.x;
  int jb = blockIdx.y*64;
  if (n >= N) return;
  float acc[64];
  #pragma unroll
  for (int j = 0; j < 64; j++) acc[j] = bias[jb + j];
  for (int k = 0; k < 128; k++){
    float x = inT[(size_t)k*N + n];
    #pragma unroll
    for (int j = 0; j < 64; j++) acc[j] = fmaf(x, W[k*128 + jb + j], acc[j]);
  }
  #pragma unroll
  for (int j = 0; j < 64; j++) outT[(size_t)(jb + j)*N + n] = fmaxf(acc[j], 0.f);
}

__global__ __launch_bounds__(256) void layer3_k(
    const float* __restrict__ X2T, const float* __restrict__ nodesT,
    const float* __restrict__ W, const float* __restrict__ bias,
    const float* __restrict__ ln_scale, const float* __restrict__ ln_bias,
    float* __restrict__ out, int N)
{
  int n = blockIdx.x*256 + threadIdx.x;
  if (n >= N) return;
  float acc[64];
  #pragma unroll
  for (int j = 0; j < 64; j++) acc[j] = bias[j];
  for (int k = 0; k < 128; k++){
    float x = X2T[(size_t)k*N + n];
    #pragma unroll
    for (int j = 0; j < 64; j++) acc[j] = fmaf(x, W[k*64 + j], acc[j]);
  }
  for (int k = 0; k < 64; k++){
    float x = nodesT[(size_t)k*N + n];
    #pragma unroll
    for (int j = 0; j < 64; j++) acc[j] = fmaf(x, W[(128 + k)*64 + j], acc[j]);
  }
  float mu = 0.f;
  #pragma unroll
  for (int j = 0; j < 64; j++) mu += acc[j];
  mu *= (1.f/64.f);
  float var = 0.f;
  #pragma unroll
  for (int j = 0; j < 64; j++){ float d = acc[j] - mu; var = fmaf(d, d, var); }
  var *= (1.f/64.f);
  float inv = rsqrtf(var + 1e-6f);
  float4* o = (float4*)(out + (size_t)n*64);
  #pragma unroll
  for (int q = 0; q < 16; q++){
    float y0 = (acc[4*q+0] - mu)*inv*ln_scale[4*q+0] + ln_bias[4*q+0];
    float y1 = (acc[4*q+1] - mu)*inv*ln_scale[4*q+1] + ln_bias[4*q+1];
    float y2 = (acc[4*q+2] - mu)*inv*ln_scale[4*q+2] + ln_bias[4*q+2];
    float y3 = (acc[4*q+3] - mu)*inv*ln_scale[4*q+3] + ln_bias[4*q+3];
    o[q] = make_float4(y0, y1, y2, y3);
  }
}

// ---------------- launch ----------------

extern "C" void kernel_launch(void* const* d_in, const int* in_sizes, int n_in,
                              void* d_out, int out_size, void* d_ws, size_t ws_size,
                              hipStream_t stream)
{
  const float* nodes   = (const float*)d_in[0];
  const float* edges   = (const float*)d_in[1];
  const int*   senders = (const int*)d_in[2];
  const int*   recv    = (const int*)d_in[3];
  const float* Wmsg    = (const float*)d_in[4];
  const float* Wnode   = (const float*)d_in[5];
  const float* w0      = (const float*)d_in[6];
  const float* b0      = (const float*)d_in[7];
  const float* w1      = (const float*)d_in[8];
  const float* b1      = (const float*)d_in[9];
  const float* w2      = (const float*)d_in[10];
  const float* b2      = (const float*)d_in[11];
  const float* lns     = (const float*)d_in[12];
  const float* lnb     = (const float*)d_in[13];
  float* out = (float*)d_out;

  const int N = in_sizes[0] / 64;
  const int E = in_sizes[2];

  auto align256 = [](size_t x){ return (x + 255) & ~(size_t)255; };
  char* p = (char*)d_ws;
  int* hist    = (int*)p; p += align256((size_t)N*4);
  int* offsets = (int*)p; p += align256((size_t)N*4);
  int* cursor  = (int*)p; p += align256((size_t)N*4);
  int* partial = (int*)p; p += align256(1024);
  int2* csr_pack = (int2*)p; p += align256((size_t)E*8);
  float* W1eff = (float*)p; p += align256((size_t)192*128*4);
  float* W3eff = (float*)p; p += align256((size_t)192*64*4);
  float* nodesT= (float*)p; p += align256((size_t)64*N*4);
  float* bufA  = (float*)p; p += align256((size_t)128*N*4);  // SE row-major, later X1_T
  float* bufB  = (float*)p; p += align256((size_t)128*N*4);  // SE_T, later X2_T

  hipMemsetAsync(hist, 0, (size_t)N*4, stream);

  const int gridE = (E + 255)/256;
  const int nb    = (N + 255)/256;

  hist_k<<<gridE, 256, 0, stream>>>(recv, hist, E);
  s1_k<<<nb, 256, 0, stream>>>(hist, partial, N);
  s2_k<<<1, 64, 0, stream>>>(partial, nb);
  s3_k<<<nb, 256, 0, stream>>>(hist, partial, offsets, cursor, N);
  fill_k<<<gridE, 256, 0, stream>>>(recv, senders, cursor, csr_pack, E);

  gather_sum_k<<<(N + 3)/4, 256, 0, stream>>>(nodes, edges, csr_pack, offsets, hist, bufA, N);

  dim3 tb(32, 8);
  transpose_k<<<dim3(2, (N + 31)/32), tb, 0, stream>>>(nodes, nodesT, N, 64);
  transpose_k<<<dim3(4, (N + 31)/32), tb, 0, stream>>>(bufA, bufB, N, 128);

  wprep_k<<<(192*128 + 255)/256, 256, 0, stream>>>(Wmsg, w0, w2, Wnode, W1eff, W3eff);

  layer1_k<<<dim3(nb, 2), 256, 0, stream>>>(nodesT, bufB, W1eff, b0, bufA, N);
  layer2_k<<<dim3(nb, 2), 256, 0, stream>>>(bufA, w1, b1, bufB, N);
  layer3_k<<<nb, 256, 0, stream>>>(bufB, nodesT, W3eff, b2, lns, lnb, out, N);
}